// Round 2
// baseline (466.225 us; speedup 1.0000x reference)
//
#include <hip/hip_runtime.h>

// SparseInputLayer: inputs [B, ND*(1+NS)] fp32.
//  - cols [0,64): channel indices (float-encoded ints in [0,384))
//  - cols [64, 64+64*121): data rows x[b][j][s]
// out[b][c][s] = sum_{j: idx[b][j]==c} x[b][j][s], shape [2048,384,121,1] fp32.
//
// Strategy: one block per batch. Scatter->gather inversion via per-channel
// 64-bit membership bitmask in LDS, then stream the output row as aligned
// float4 stores (16 B/lane — the coalescing sweet spot). Each float4 spans
// at most 2 channels; both masks are preloaded as independent LDS reads so
// there is no mid-iteration LDS dependency chain.

#define BATCH 2048
#define N_DENSE 64
#define N_SAMPLES 121
#define N_CHANNELS 384
#define ROW_IN (N_DENSE * (1 + N_SAMPLES)) // 7808 floats per input row
#define ROW_OUT (N_CHANNELS * N_SAMPLES)   // 46464 floats per output row
#define NVEC (ROW_OUT / 4)                 // 11616 float4 per output row
#define BLOCK 256

typedef float vfloat4 __attribute__((ext_vector_type(4)));

__global__ __launch_bounds__(BLOCK) void sparse_scatter_kernel(
    const float* __restrict__ in, float* __restrict__ out) {
  // +1 pad so mask[c+1] is always a valid read (c can be 383 for the tail)
  __shared__ unsigned long long mask[N_CHANNELS + 1];

  const int b = blockIdx.x;
  const int tid = threadIdx.x;

  for (int c = tid; c < N_CHANNELS + 1; c += BLOCK) mask[c] = 0ull;
  __syncthreads();

  // threads 0..63 each own dense slot j; set bit j in its channel's mask
  if (tid < N_DENSE) {
    const int c = (int)in[(size_t)b * ROW_IN + tid];
    atomicOr(&mask[c], 1ull << tid);
  }
  __syncthreads();

  const float* __restrict__ x = in + (size_t)b * ROW_IN + N_DENSE; // [64][121]
  float* __restrict__ o = out + (size_t)b * ROW_OUT;               // [384][121]

  for (int q = tid; q < NVEC; q += BLOCK) {
    const int e = q * 4;                   // first output element of this vec
    const int c = e / N_SAMPLES;           // magic-mul div
    const int s0 = e - c * N_SAMPLES;
    // two independent LDS loads, issued back-to-back (latency overlaps)
    const unsigned long long m0 = mask[c];
    const unsigned long long m1 = mask[c + 1];

    vfloat4 v;
#pragma unroll
    for (int i = 0; i < 4; ++i) {
      int s = s0 + i;
      unsigned long long m = m0;
      if (s >= N_SAMPLES) { s -= N_SAMPLES; m = m1; } // crossed channel bound
      float sum = 0.0f;
      while (m) {                       // rare: ~85% of channels are empty
        const int j = __builtin_ctzll(m);
        m &= m - 1;
        sum += x[j * N_SAMPLES + s];    // read-once stream, 63.5 MB total
      }
      v[i] = sum;
    }
    // aligned 16B coalesced store (o + e is 16B-aligned: e%4==0, row%16B==0)
    *reinterpret_cast<vfloat4*>(o + e) = v;
  }
}

extern "C" void kernel_launch(void* const* d_in, const int* in_sizes, int n_in,
                              void* d_out, int out_size, void* d_ws, size_t ws_size,
                              hipStream_t stream) {
  const float* in = (const float*)d_in[0];
  float* out = (float*)d_out;
  sparse_scatter_kernel<<<BATCH, BLOCK, 0, stream>>>(in, out);
}

// Round 3
// 457.848 us; speedup vs baseline: 1.0183x; 1.0183x over previous
//
#include <hip/hip_runtime.h>

// SparseInputLayer: inputs [B, ND*(1+NS)] fp32.
//  - cols [0,64): channel indices (float-encoded ints in [0,384))
//  - cols [64, ...): data rows x[b][j][s]
// out[b][c][s] = sum_{j: idx[b][j]==c} x[b][j][s], shape [2048,384,121,1] fp32.
//
// Two-phase, one block per batch:
//  Phase A: branchless float4 zero-fill of the block's 46464-float output row
//           (pure store stream, matches fillBufferAligned's 6.2 TB/s pattern).
//  Phase B: overwrite the ~59 nonempty channels (compacted list in LDS), one
//           wave per channel, wave-uniform 64-bit membership mask (no lane
//           divergence in the bit-walk). Only ~59 MB re-written (+15%).

#define BATCH 2048
#define N_DENSE 64
#define N_SAMPLES 121
#define N_CHANNELS 384
#define ROW_IN (N_DENSE * (1 + N_SAMPLES)) // 7808 floats per input row
#define ROW_OUT (N_CHANNELS * N_SAMPLES)   // 46464 floats per output row
#define NVEC (ROW_OUT / 4)                 // 11616 float4 per output row
#define BLOCK 256

typedef float vfloat4 __attribute__((ext_vector_type(4)));

__global__ __launch_bounds__(BLOCK) void sparse_scatter_kernel(
    const float* __restrict__ in, float* __restrict__ out) {
  __shared__ unsigned long long mask[N_CHANNELS];
  __shared__ unsigned short list[N_CHANNELS]; // compacted nonempty channels
  __shared__ int nlist;

  const int b = blockIdx.x;
  const int tid = threadIdx.x;

  for (int c = tid; c < N_CHANNELS; c += BLOCK) mask[c] = 0ull;
  if (tid == 0) nlist = 0;
  __syncthreads();

  if (tid < N_DENSE) {
    const int c = (int)in[(size_t)b * ROW_IN + tid];
    atomicOr(&mask[c], 1ull << tid);
  }
  __syncthreads();

  // compact the nonempty channels (~59 of 384 expected)
  for (int c = tid; c < N_CHANNELS; c += BLOCK) {
    if (mask[c] != 0ull) {
      const int p = atomicAdd(&nlist, 1);
      list[p] = (unsigned short)c;
    }
  }

  float* __restrict__ o = out + (size_t)b * ROW_OUT;

  // ---- Phase A: pure zero-fill stream (no LDS, no branches, no deps) ----
  {
    const vfloat4 z = {0.f, 0.f, 0.f, 0.f};
    vfloat4* __restrict__ ov = reinterpret_cast<vfloat4*>(o);
    for (int q = tid; q < NVEC; q += BLOCK) ov[q] = z; // 46 aligned 16B stores
  }
  __syncthreads(); // drains phase-A stores (vmcnt(0)) before overwrites

  // ---- Phase B: one wave per nonempty channel ----
  const float* __restrict__ x = in + (size_t)b * ROW_IN + N_DENSE; // [64][121]
  const int wave = tid >> 6;
  const int lane = tid & 63;
  const int n = nlist;
  const int s = lane * 2; // lanes cover 121 samples as pairs (lane 60: 1 elt)

  for (int i = wave; i < n; i += BLOCK / 64) {
    const int c = __builtin_amdgcn_readfirstlane((int)list[i]); // scalar base
    unsigned long long m = mask[c]; // same LDS addr all lanes -> uniform
    float a0 = 0.f, a1 = 0.f;
    while (m) { // wave-uniform trip count: no divergence
      const int j = __builtin_ctzll(m);
      m &= m - 1;
      a0 += x[j * N_SAMPLES + s];     // coalesced 484B row read
      a1 += x[j * N_SAMPLES + s + 1];
    }
    float* oc = o + c * N_SAMPLES;
    if (s < N_SAMPLES - 1) {
      oc[s] = a0;
      oc[s + 1] = a1;
    } else if (s == N_SAMPLES - 1) {
      oc[s] = a0;
    }
  }
}

extern "C" void kernel_launch(void* const* d_in, const int* in_sizes, int n_in,
                              void* d_out, int out_size, void* d_ws, size_t ws_size,
                              hipStream_t stream) {
  const float* in = (const float*)d_in[0];
  float* out = (float*)d_out;
  sparse_scatter_kernel<<<BATCH, BLOCK, 0, stream>>>(in, out);
}